// Round 9
// baseline (233.659 us; speedup 1.0000x reference)
//
#include <hip/hip_runtime.h>

// Problem constants (from reference setup_inputs):
//   fm0: [16,3,80,80,85]  -> 26,112,000 floats, 19200 rows/batch, scale 80
//   fm1: [16,3,40,40,85]  ->  6,528,000 floats,  4800 rows/batch, scale 40
//   fm2: [16,3,20,20,85]  ->  1,632,000 floats,  1200 rows/batch, scale 20
//   out: [16, 25200, 85]  -> 34,272,000 floats
//
// Round-9: round-8 (best: dur 232.4, kernel ~68 us) with the one
// never-varied knob moved: block size 256 -> 128 (66,938 one-shot blocks).
// Mechanism under test (3x confirmed): freshly dispatched blocks issue
// their loads with no intra-thread vmcnt dependency -> block churn IS the
// memory pipeline; finer block granularity = more independent issue units.
// 128 is the floor of this knob: 16 workgroups/CU HW limit x 2 waves = 32
// waves/CU (full); 64-thread blocks would halve resident waves.
// Kernel body unchanged from round 8 (harness-verified, absmax 0.0039).
#define NROWS_OUT 25200
#define L0_FLOATS 26112000
#define L1_FLOATS 6528000
#define L2_FLOATS 1632000
#define TOTAL_FLOATS (L0_FLOATS + L1_FLOATS + L2_FLOATS)   // 34,272,000
#define TOTAL4   (TOTAL_FLOATS / 4)                        //  8,568,000
#define BLOCK    128

typedef float v4f __attribute__((ext_vector_type(4)));

__device__ __forceinline__ float fast_sigmoid(float x) {
    // v_exp_f32 (+1 mul) + v_rcp_f32: ~4 VALU ops, rel err ~1e-6.
    float e = __expf(-x);
    return __builtin_amdgcn_rcpf(1.0f + e);
}

// One aligned float4 of a level's flat buffer. ROWS/OFF/SCALE compile-time.
// Harness-verified in rounds 3/4/5/8 (absmax 0.0039, passed).
//
// Alignment: f_local % 4 == 0; output shift per (b,level) is a multiple of
// 4 floats for all levels, so load and store are 16B-aligned.
//
// Row-float reconstruction (1 vec load instead of 4 scalar loads):
//   needed row floats beyond our own x are all inside ONE aligned neighbor
//   float4: prev (f-4) for c0 in 1..3, next (f+4) for c0 in 82..84, none
//   otherwise (neighbor load degenerates to own address -> L1 hit).
//   In-bounds: c0 in 1..3 => f>=4; c0>=82 => next row exists in full (last
//   float4 of a level has c0 = (ROWS85-4) % 85 = 81, never >=82).
template <int ROWS, int OFF, int SCALE>
__device__ __forceinline__ void process4(const float* __restrict__ in,
                                         float* __restrict__ out,
                                         int f_local) {
    constexpr int ROWS85 = ROWS * 85;
    const int b   = f_local / ROWS85;          // magic-mul (const divisor)
    const int rem = f_local - b * ROWS85;      // j*85 + c within batch
    const int c0  = rem % 85;                  // channel of first element

    const bool prevNeeded = (c0 >= 1) && (c0 <= 3);
    const bool nextNeeded = (c0 >= 82);
    int nb = f_local;                          // dummy: own address
    if (prevNeeded) nb = f_local - 4;
    if (nextNeeded) nb = f_local + 4;

    const v4f x = *(const v4f*)(in + f_local);
    const v4f n = *(const v4f*)(in + nb);

    // 7-wide window, static names only (rule #20: no runtime-indexed arrays)
    const float w0 = prevNeeded ? n.x : x.x;
    const float w1 = prevNeeded ? n.y : x.y;
    const float w2 = prevNeeded ? n.z : x.z;
    const float w3 = prevNeeded ? n.w : x.w;
    const float w4 = prevNeeded ? x.x : n.x;
    const float w5 = prevNeeded ? x.y : n.y;
    const float w6 = prevNeeded ? x.z : n.z;
    const int idx = prevNeeded ? (4 - c0) : (nextNeeded ? (85 - c0) : 0);
    const bool i1 = (idx & 1) != 0;
    const bool i2 = (idx & 2) != 0;
    // funnel shift by idx (0..3): shift 2, then shift 1
    const float a0 = i2 ? w2 : w0;
    const float a1 = i2 ? w3 : w1;
    const float a2 = i2 ? w4 : w2;
    const float a3 = i2 ? w5 : w3;
    const float a4 = i2 ? w6 : w4;
    const float r0 = i1 ? a1 : a0;
    const float r1 = i1 ? a2 : a1;
    const float r2 = i1 ? a3 : a2;
    const float r3 = i1 ? a4 : a3;

    // Faithful to the torch in-place sequence (W == H == SCALE):
    const float sc = (float)SCALE;
    const float h2 = 0.5f * r2, h3 = 0.5f * r3;
    const float q0 = (r0 - h2) * sc;           // x1
    const float q1 = (r1 - h3) * sc;           // y1
    const float q2 = (q0 + h2) * sc;           // x2
    const float q3 = (q1 + h3) * sc;           // y2

    float xv[4] = {x.x, x.y, x.z, x.w};
    float y[4];
#pragma unroll
    for (int k = 0; k < 4; ++k) {
        int c = c0 + k;
        if (c >= 85) c -= 85;                  // at most one row wrap
        const float s = fast_sigmoid(xv[k]);
        const float q = (c == 0) ? q0 : ((c == 1) ? q1 : ((c == 2) ? q2 : q3));
        y[k] = (c < 4) ? q : s;                // v_cndmask chain, no branch
    }

    const int out_f = (b * NROWS_OUT + OFF) * 85 + rem;
    v4f yo; yo.x = y[0]; yo.y = y[1]; yo.z = y[2]; yo.w = y[3];
    __builtin_nontemporal_store(yo, (v4f*)(out + out_f));
}

__device__ __forceinline__ void dispatch4(const float* __restrict__ fm0,
                                          const float* __restrict__ fm1,
                                          const float* __restrict__ fm2,
                                          float* __restrict__ out, int f) {
    if (f < L0_FLOATS) {                       // 76.2% of threads
        process4<19200, 0, 80>(fm0, out, f);
    } else if (f < L0_FLOATS + L1_FLOATS) {
        process4<4800, 19200, 40>(fm1, out, f - L0_FLOATS);
    } else {
        process4<1200, 24000, 20>(fm2, out, f - (L0_FLOATS + L1_FLOATS));
    }
}

__global__ __launch_bounds__(BLOCK) void yolo_decode_kernel(
    const float* __restrict__ fm0, const float* __restrict__ fm1,
    const float* __restrict__ fm2, float* __restrict__ out) {
    // One float4 per thread: maximal block-level load parallelism, minimal
    // per-thread serial convoy. Consecutive lanes -> consecutive float4s.
    const int v = blockIdx.x * BLOCK + threadIdx.x;
    if (v >= TOTAL4) return;
    dispatch4(fm0, fm1, fm2, out, v * 4);
}

extern "C" void kernel_launch(void* const* d_in, const int* in_sizes, int n_in,
                              void* d_out, int out_size, void* d_ws, size_t ws_size,
                              hipStream_t stream) {
    const float* fm0 = (const float*)d_in[0];
    const float* fm1 = (const float*)d_in[1];
    const float* fm2 = (const float*)d_in[2];
    float* out = (float*)d_out;

    const int blocks = (TOTAL4 + BLOCK - 1) / BLOCK;   // 66,938
    hipLaunchKernelGGL(yolo_decode_kernel, dim3(blocks), dim3(BLOCK), 0, stream,
                       fm0, fm1, fm2, out);
}

// Round 10
// 232.713 us; speedup vs baseline: 1.0041x; 1.0041x over previous
//
#include <hip/hip_runtime.h>

// Problem constants (from reference setup_inputs):
//   fm0: [16,3,80,80,85]  -> 26,112,000 floats, 19200 rows/batch, scale 80
//   fm1: [16,3,40,40,85]  ->  6,528,000 floats,  4800 rows/batch, scale 40
//   fm2: [16,3,20,20,85]  ->  1,632,000 floats,  1200 rows/batch, scale 20
//   out: [16, 25200, 85]  -> 34,272,000 floats
//
// FINAL (round-10 = round-8 restored verbatim, the session best: 232.4 us).
// Round-9 (128-thread blocks) was +1.2 us -> 256-thread blocks stand.
//
// Session conclusions baked into this kernel:
//   - 1 float4 per thread, one-shot grid of 33,469 blocks: per-thread work
//     4->2->1 f4 was the ONLY lever that moved perf (84 -> ~72 -> ~68 us
//     kernel time). Freshly dispatched blocks issue loads with no
//     intra-thread vmcnt dependency: block churn IS the memory pipeline.
//   - 3 VMEM per thread (1 main dwordx4 + 1 aligned-neighbor dwordx4 + 1 NT
//     store): halving VMEM vs the 6-instr version was perf-null but keeps
//     L1 traffic minimal; funnel-select reconstruction harness-verified.
//   - NT stores ~5% better than plain (r0/r3 vs r2).
//   - Falsified levers (do not revisit): grid-stride persistent blocks
//     (-10 us), VALU-count cuts, kernel split, forced intra-thread ILP
//     (compiler keeps VGPR=24 and re-serializes), block size 128.
#define NROWS_OUT 25200
#define L0_FLOATS 26112000
#define L1_FLOATS 6528000
#define L2_FLOATS 1632000
#define TOTAL_FLOATS (L0_FLOATS + L1_FLOATS + L2_FLOATS)   // 34,272,000
#define TOTAL4   (TOTAL_FLOATS / 4)                        //  8,568,000

typedef float v4f __attribute__((ext_vector_type(4)));

__device__ __forceinline__ float fast_sigmoid(float x) {
    // v_exp_f32 (+1 mul) + v_rcp_f32: ~4 VALU ops, rel err ~1e-6.
    float e = __expf(-x);
    return __builtin_amdgcn_rcpf(1.0f + e);
}

// One aligned float4 of a level's flat buffer. ROWS/OFF/SCALE compile-time.
// Harness-verified in rounds 3/4/5/8/9 (absmax 0.0039, passed).
//
// Alignment: f_local % 4 == 0; output shift per (b,level) is a multiple of
// 4 floats for all levels, so load and store are 16B-aligned.
//
// Row-float reconstruction (1 vec load instead of 4 scalar loads):
//   needed row floats beyond our own x are all inside ONE aligned neighbor
//   float4: prev (f-4) for c0 in 1..3, next (f+4) for c0 in 82..84, none
//   otherwise (neighbor load degenerates to own address -> L1 hit).
//   In-bounds: c0 in 1..3 => f>=4; c0>=82 => next row exists in full (last
//   float4 of a level has c0 = (ROWS85-4) % 85 = 81, never >=82).
template <int ROWS, int OFF, int SCALE>
__device__ __forceinline__ void process4(const float* __restrict__ in,
                                         float* __restrict__ out,
                                         int f_local) {
    constexpr int ROWS85 = ROWS * 85;
    const int b   = f_local / ROWS85;          // magic-mul (const divisor)
    const int rem = f_local - b * ROWS85;      // j*85 + c within batch
    const int c0  = rem % 85;                  // channel of first element

    const bool prevNeeded = (c0 >= 1) && (c0 <= 3);
    const bool nextNeeded = (c0 >= 82);
    int nb = f_local;                          // dummy: own address
    if (prevNeeded) nb = f_local - 4;
    if (nextNeeded) nb = f_local + 4;

    const v4f x = *(const v4f*)(in + f_local);
    const v4f n = *(const v4f*)(in + nb);

    // 7-wide window, static names only (rule #20: no runtime-indexed arrays)
    const float w0 = prevNeeded ? n.x : x.x;
    const float w1 = prevNeeded ? n.y : x.y;
    const float w2 = prevNeeded ? n.z : x.z;
    const float w3 = prevNeeded ? n.w : x.w;
    const float w4 = prevNeeded ? x.x : n.x;
    const float w5 = prevNeeded ? x.y : n.y;
    const float w6 = prevNeeded ? x.z : n.z;
    const int idx = prevNeeded ? (4 - c0) : (nextNeeded ? (85 - c0) : 0);
    const bool i1 = (idx & 1) != 0;
    const bool i2 = (idx & 2) != 0;
    // funnel shift by idx (0..3): shift 2, then shift 1
    const float a0 = i2 ? w2 : w0;
    const float a1 = i2 ? w3 : w1;
    const float a2 = i2 ? w4 : w2;
    const float a3 = i2 ? w5 : w3;
    const float a4 = i2 ? w6 : w4;
    const float r0 = i1 ? a1 : a0;
    const float r1 = i1 ? a2 : a1;
    const float r2 = i1 ? a3 : a2;
    const float r3 = i1 ? a4 : a3;

    // Faithful to the torch in-place sequence (W == H == SCALE):
    const float sc = (float)SCALE;
    const float h2 = 0.5f * r2, h3 = 0.5f * r3;
    const float q0 = (r0 - h2) * sc;           // x1
    const float q1 = (r1 - h3) * sc;           // y1
    const float q2 = (q0 + h2) * sc;           // x2
    const float q3 = (q1 + h3) * sc;           // y2

    float xv[4] = {x.x, x.y, x.z, x.w};
    float y[4];
#pragma unroll
    for (int k = 0; k < 4; ++k) {
        int c = c0 + k;
        if (c >= 85) c -= 85;                  // at most one row wrap
        const float s = fast_sigmoid(xv[k]);
        const float q = (c == 0) ? q0 : ((c == 1) ? q1 : ((c == 2) ? q2 : q3));
        y[k] = (c < 4) ? q : s;                // v_cndmask chain, no branch
    }

    const int out_f = (b * NROWS_OUT + OFF) * 85 + rem;
    v4f yo; yo.x = y[0]; yo.y = y[1]; yo.z = y[2]; yo.w = y[3];
    __builtin_nontemporal_store(yo, (v4f*)(out + out_f));
}

__device__ __forceinline__ void dispatch4(const float* __restrict__ fm0,
                                          const float* __restrict__ fm1,
                                          const float* __restrict__ fm2,
                                          float* __restrict__ out, int f) {
    if (f < L0_FLOATS) {                       // 76.2% of threads
        process4<19200, 0, 80>(fm0, out, f);
    } else if (f < L0_FLOATS + L1_FLOATS) {
        process4<4800, 19200, 40>(fm1, out, f - L0_FLOATS);
    } else {
        process4<1200, 24000, 20>(fm2, out, f - (L0_FLOATS + L1_FLOATS));
    }
}

__global__ __launch_bounds__(256) void yolo_decode_kernel(
    const float* __restrict__ fm0, const float* __restrict__ fm1,
    const float* __restrict__ fm2, float* __restrict__ out) {
    // One float4 per thread: maximal block-level load parallelism, minimal
    // per-thread serial convoy. Consecutive lanes -> consecutive float4s.
    const int v = blockIdx.x * 256 + threadIdx.x;
    if (v >= TOTAL4) return;
    dispatch4(fm0, fm1, fm2, out, v * 4);
}

extern "C" void kernel_launch(void* const* d_in, const int* in_sizes, int n_in,
                              void* d_out, int out_size, void* d_ws, size_t ws_size,
                              hipStream_t stream) {
    const float* fm0 = (const float*)d_in[0];
    const float* fm1 = (const float*)d_in[1];
    const float* fm2 = (const float*)d_in[2];
    float* out = (float*)d_out;

    const int blocks = (TOTAL4 + 255) / 256;   // 33,469
    hipLaunchKernelGGL(yolo_decode_kernel, dim3(blocks), dim3(256), 0, stream,
                       fm0, fm1, fm2, out);
}